// Round 8
// baseline (192.852 us; speedup 1.0000x reference)
//
#include <hip/hip_runtime.h>

// Problem constants
#define VD 160           // vol D=H=W
#define OD 128           // output crop size
#define CROP0 16         // (160-128)/2
#define FSZ 11           // cropped field size
#define RAWSZ 15         // raw field size
#define NBATCH 4
#define ODQ 2            // outputs per thread along od

// e-table (LDS): rows [c(3)][oh(8)*8 + od_l(8)], row stride ESTR floats.
#define ESTR 17
#define E_CST (64*ESTR)    // channel stride = 1088 floats

// vol slab (LDS): FIXED geometry [ZMAX][PLS], row stride XSTR floats.
// All compile-time -> staging/compute index math is magic-mul only.
#define XSTR 33
#define PLS  576           // 17.45 rows; 9 64-float chunks per plane, exact
#define ZMAX 22
#define SLABF (ZMAX*PLS)   // 12672 floats = 50688 B
// total static LDS = 13056(e) + 50688(slab) + 256(red) = 64000 B  (< 64 KB)

// ---------------------------------------------------------------------------
// Compile-time (box-5 edge-clamp)^4 as a 15x15 matrix.
// ---------------------------------------------------------------------------
struct M15 { float v[15][15]; };
constexpr M15 mkB() {
    M15 b{};
    for (int i = 0; i < 15; ++i)
        for (int j = 0; j < 15; ++j) b.v[i][j] = 0.0f;
    for (int i = 0; i < 15; ++i)
        for (int t = -2; t <= 2; ++t) {
            int j = i + t; j = j < 0 ? 0 : (j > 14 ? 14 : j);
            b.v[i][j] += 0.2f;
        }
    return b;
}
constexpr M15 mmul(const M15& a, const M15& b) {
    M15 c{};
    for (int i = 0; i < 15; ++i)
        for (int j = 0; j < 15; ++j) {
            float s = 0.0f;
            for (int k = 0; k < 15; ++k) s += a.v[i][k] * b.v[k][j];
            c.v[i][j] = s;
        }
    return c;
}
constexpr M15 B2 = mmul(mkB(), mkB());
constexpr M15 B4 = mmul(B2, B2);

// ---------------------------------------------------------------------------
// Kernel 1: field prep (blocks 0..2) + Rodrigues/theta (block 3).  (proven)
// ---------------------------------------------------------------------------
__global__ __launch_bounds__(1024) void prep_kernel(
        const float* __restrict__ rot, const float* __restrict__ scale,
        const float* __restrict__ shift,
        const float* __restrict__ dz, const float* __restrict__ dy,
        const float* __restrict__ dx,
        float* __restrict__ theta, float* __restrict__ fields) {
    const int tid = threadIdx.x;
    const int chan = blockIdx.x;

    if (chan == 3) {
        int n = tid;
        if (n >= NBATCH) return;
        float rx = rot[n*3+0], ry = rot[n*3+1], rz = rot[n*3+2];
        float t2 = rx*rx + ry*ry + rz*rz;
        const float eps = 1e-6f;
        float th = sqrtf(fmaxf(t2, eps));
        float inv = 1.0f / (th + eps);
        float wx = rx*inv, wy = ry*inv, wz = rz*inv;
        float c = cosf(th), s = sinf(th), k = 1.0f - c;
        float R[9];
        if (t2 > eps) {
            R[0] = c + wx*wx*k;      R[1] = wx*wy*k - wz*s;  R[2] = wy*s + wx*wz*k;
            R[3] = wz*s + wx*wy*k;   R[4] = c + wy*wy*k;     R[5] = -wx*s + wy*wz*k;
            R[6] = -wy*s + wx*wz*k;  R[7] = wx*s + wy*wz*k;  R[8] = c + wz*wz*k;
        } else {
            R[0] = 1.0f; R[1] = -rz;  R[2] = ry;
            R[3] = rz;   R[4] = 1.0f; R[5] = -rx;
            R[6] = -ry;  R[7] = rx;   R[8] = 1.0f;
        }
        for (int i = 0; i < 3; ++i) {
            for (int j = 0; j < 3; ++j)
                theta[n*12 + i*4 + j] = R[i*3 + j] * scale[n*3 + j];
            theta[n*12 + i*4 + 3] = shift[n*3 + i];
        }
        return;
    }

    __shared__ float bufA[RAWSZ*RAWSZ*RAWSZ];   // raw scaled  [z][y][x]
    __shared__ float bufB[RAWSZ*RAWSZ*FSZ];     // x-pass out  [z][y][xo]
    __shared__ float bufC[RAWSZ*FSZ*FSZ];       // y-pass out  [z][yo][xo]
    const float* raw = (chan == 0) ? dz : (chan == 1) ? dy : dx;
    const int NTOT = RAWSZ*RAWSZ*RAWSZ;   // 3375

    for (int i = tid; i < NTOT; i += 1024)
        bufA[i] = (raw[i] - 0.5f) * 4.0f;
    __syncthreads();

    for (int i = tid; i < RAWSZ*RAWSZ*FSZ; i += 1024) {
        const int zy = i / FSZ;
        const int xo = i % FSZ;
        const float* row = &bufA[zy * RAWSZ];
        const float* w = B4.v[xo + 2];
        float s = 0.0f;
        #pragma unroll
        for (int j = 0; j < RAWSZ; ++j) s += row[j] * w[j];
        bufB[i] = s;
    }
    __syncthreads();

    for (int i = tid; i < RAWSZ*FSZ*FSZ; i += 1024) {
        const int z  = i / (FSZ*FSZ);
        const int r  = i % (FSZ*FSZ);
        const int yo = r / FSZ;
        const int xo = r % FSZ;
        const float* base = &bufB[z * (RAWSZ*FSZ) + xo];
        const float* w = B4.v[yo + 2];
        float s = 0.0f;
        #pragma unroll
        for (int j = 0; j < RAWSZ; ++j) s += base[j * FSZ] * w[j];
        bufC[i] = s;
    }
    __syncthreads();

    for (int i = tid; i < FSZ*FSZ*FSZ; i += 1024) {
        const int zo = i / (FSZ*FSZ);
        const int r  = i % (FSZ*FSZ);
        const float* base = &bufC[r];
        const float* w = B4.v[zo + 2];
        float s = 0.0f;
        #pragma unroll
        for (int j = 0; j < RAWSZ; ++j) s += base[j * (FSZ*FSZ)] * w[j];
        fields[chan*FSZ*FSZ*FSZ + i] = s;
    }
}

// ---------------------------------------------------------------------------
// resize helper: src = (m+0.5)*(11/160) - 0.5, clipped to [0,10]
// ---------------------------------------------------------------------------
__device__ __forceinline__ void resize_coord(int m, int& i0, int& i1, float& w) {
    float s = fmaf((float)m + 0.5f, (float)FSZ / (float)VD, -0.5f);
    s = fminf(fmaxf(s, 0.0f), (float)(FSZ - 1));
    float f = floorf(s);
    i0 = (int)f;
    i1 = min(i0 + 1, FSZ - 1);
    w = s - f;
}

// ---------------------------------------------------------------------------
// Kernel 2: main sampler. Output tile 16(w) x 8(h) x 8(d) per 512-thr block.
// Wave = 16(wl) x 4(hl); 8 waves = 2(wh) x 4(wd); ODQ=2 od's per thread.
//
// R5 proved: not VALU-bound, not latency-bound (16 forced in-flight loads
// flat). Remaining suspect: L1/TA scattered-request service. Test: stage the
// block's bounding slab of vol into LDS with ASYNC global_load_lds (no VGPR
// round trip, all issues before one barrier drain), serve all 8 trilinear
// taps from LDS. Fixed [22][576] slab geometry -> compile-time index math,
// no runtime-divisor loops. fits/border fallback -> proven global path.
// grid = (OD/16, OD/8, (OD/8)*NBATCH).
// ---------------------------------------------------------------------------
__global__ __launch_bounds__(512) void sample_kernel(
        const float* __restrict__ vol, const float* __restrict__ theta,
        const float* __restrict__ fields, float* __restrict__ out) {
    __shared__ float e[3*E_CST];     // 13056 B
    __shared__ float slab[SLABF];    // 50688 B
    __shared__ int   red[8][8];      // 256 B   (per-wave min/max scratch)

    const int tid  = threadIdx.x;
    const int lane = tid & 63;
    const int wl   = lane & 15;        // ow within wave
    const int hl   = lane >> 4;        // 0..3
    const int wv   = tid >> 6;         // wave id 0..7
    const int wh   = wv & 1;
    const int wd   = wv >> 1;          // 0..3

    const int ow   = (blockIdx.x << 4) | wl;        // 0..127
    const int oh_l = (wh << 2) | hl;                // 0..7
    const int oh   = (blockIdx.y << 3) | oh_l;      // 0..127
    const int odb  = (blockIdx.z & 15) << 3;        // od block base
    const int n    = blockIdx.z >> 4;
    const int od0  = odb + (wd << 1);

    // ---- e fill: 64 rows (oh*8+od) x 16 xi slots, 2 rows/thread ----
    {
        const int xi = tid & 15;
        const int rb = tid >> 4;        // 0..31 = oh0*8 + od_l (oh0 in 0..3)
        if (xi < FSZ) {
            const int od_l = rb & 7;
            const int oh0  = rb >> 3;
            int zi0, zi1, yA0, yA1, yB0, yB1;
            float zw, ywA, ywB;
            resize_coord(odb + od_l + CROP0, zi0, zi1, zw);
            const int hbase = (blockIdx.y << 3) + CROP0;
            resize_coord(hbase + oh0,     yA0, yA1, ywA);
            resize_coord(hbase + oh0 + 4, yB0, yB1, ywB);
            const float wz0 = 1.0f - zw;
            const float wA00 = wz0*(1.0f-ywA), wA01 = wz0*ywA;
            const float wA10 = zw*(1.0f-ywA),  wA11 = zw*ywA;
            const float wB00 = wz0*(1.0f-ywB), wB01 = wz0*ywB;
            const float wB10 = zw*(1.0f-ywB),  wB11 = zw*ywB;
            const int oA00 = zi0*121 + yA0*11 + xi, oA01 = zi0*121 + yA1*11 + xi;
            const int oA10 = zi1*121 + yA0*11 + xi, oA11 = zi1*121 + yA1*11 + xi;
            const int oB00 = zi0*121 + yB0*11 + xi, oB01 = zi0*121 + yB1*11 + xi;
            const int oB10 = zi1*121 + yB0*11 + xi, oB11 = zi1*121 + yB1*11 + xi;
            #pragma unroll
            for (int c = 0; c < 3; ++c) {
                const float* f = fields + c * (FSZ*FSZ*FSZ);
                e[(c*64 + rb)*ESTR + xi] =
                    80.0f * (f[oA00]*wA00 + f[oA01]*wA01 + f[oA10]*wA10 + f[oA11]*wA11);
                e[(c*64 + rb + 32)*ESTR + xi] =
                    80.0f * (f[oB00]*wB00 + f[oB01]*wB01 + f[oB10]*wB10 + f[oB11]*wB11);
            }
        }
    }

    // ---- per-thread setup (overlaps e-fill latency) ----
    const int w_ = ow + CROP0;
    const float x = fmaf(2.0f * (float)w_ + 1.0f, 1.0f / (float)VD, -1.0f);
    const float y = fmaf(2.0f * (float)(oh + CROP0) + 1.0f, 1.0f / (float)VD, -1.0f);

    float s = fmaf((float)w_ + 0.5f, (float)FSZ / (float)VD, -0.5f);
    s = fminf(fmaxf(s, 0.0f), (float)(FSZ - 1));
    const float sf = floorf(s);
    const int   xi0 = (int)sf;
    const float xw  = s - sf;

    const float* th = theta + n*12;
    const float cx = fmaf(th[0]*x + th[1]*y + th[3], 80.0f, 79.5f);
    const float cy = fmaf(th[4]*x + th[5]*y + th[7], 80.0f, 79.5f);
    const float cz = fmaf(th[8]*x + th[9]*y + th[11], 80.0f, 79.5f);
    const float tz0 = th[2] * 80.0f, tz1 = th[6] * 80.0f, tz2 = th[10] * 80.0f;

    const float* v = vol + (size_t)n * (VD*VD*VD);
    const float* ebase = &e[(oh_l*8 + (wd << 1))*ESTR + xi0];
    const float zb = fmaf(2.0f * (float)(od0 + CROP0) + 1.0f,
                          1.0f / (float)VD, -1.0f);
    float* op = out + ((((size_t)n*OD + od0)*OD + oh)*OD + ow);

    __syncthreads();                                   // B1: e ready

    // ---- e reads + coords ----
    float fx[ODQ], fy[ODQ], fz[ODQ];
    int ix[ODQ], iy[ODQ], iz[ODQ];
    int inb = 1;
    #pragma unroll
    for (int k = 0; k < ODQ; ++k) {
        const float ex0 = ebase[        k*ESTR    ], ex1 = ebase[        k*ESTR + 1];
        const float ey0 = ebase[E_CST + k*ESTR    ], ey1 = ebase[E_CST + k*ESTR + 1];
        const float ez0 = ebase[2*E_CST + k*ESTR  ], ez1 = ebase[2*E_CST + k*ESTR + 1];
        const float z = zb + (float)k * (2.0f / (float)VD);
        const float xs = fmaf(tz0, z, cx) + fmaf(ex1 - ex0, xw, ex0);
        const float ys = fmaf(tz1, z, cy) + fmaf(ey1 - ey0, xw, ey0);
        const float zs = fmaf(tz2, z, cz) + fmaf(ez1 - ez0, xw, ez0);
        const float x0f = floorf(xs), y0f = floorf(ys), z0f = floorf(zs);
        fx[k] = xs - x0f; fy[k] = ys - y0f; fz[k] = zs - z0f;
        ix[k] = (int)x0f; iy[k] = (int)y0f; iz[k] = (int)z0f;
        inb &= ((unsigned)ix[k] < (unsigned)(VD-1)) &
               ((unsigned)iy[k] < (unsigned)(VD-1)) &
               ((unsigned)iz[k] < (unsigned)(VD-1));
    }

    // ---- block min/max of int coords (contributors: inb threads only) ----
    const int BIG = 0x3fffffff;
    int mnx = inb ? min(ix[0], ix[1]) : BIG,  mxx = inb ? max(ix[0], ix[1]) : -BIG;
    int mny = inb ? min(iy[0], iy[1]) : BIG,  mxy = inb ? max(iy[0], iy[1]) : -BIG;
    int mnz = inb ? min(iz[0], iz[1]) : BIG,  mxz = inb ? max(iz[0], iz[1]) : -BIG;
    #pragma unroll
    for (int d = 1; d < 64; d <<= 1) {
        mnx = min(mnx, __shfl_xor(mnx, d));  mxx = max(mxx, __shfl_xor(mxx, d));
        mny = min(mny, __shfl_xor(mny, d));  mxy = max(mxy, __shfl_xor(mxy, d));
        mnz = min(mnz, __shfl_xor(mnz, d));  mxz = max(mxz, __shfl_xor(mxz, d));
    }
    if (lane == 0) {
        red[wv][0] = mnx; red[wv][1] = mxx;
        red[wv][2] = mny; red[wv][3] = mxy;
        red[wv][4] = mnz; red[wv][5] = mxz;
    }
    __syncthreads();                                   // B2: reductions ready

    int Mnx = BIG, Mxx = -BIG, Mny = BIG, Mxy = -BIG, Mnz = BIG, Mxz = -BIG;
    #pragma unroll
    for (int w2 = 0; w2 < 8; ++w2) {
        Mnx = min(Mnx, red[w2][0]);  Mxx = max(Mxx, red[w2][1]);
        Mny = min(Mny, red[w2][2]);  Mxy = max(Mxy, red[w2][3]);
        Mnz = min(Mnz, red[w2][4]);  Mxz = max(Mxz, red[w2][5]);
    }
    const int lox = min(max(Mnx, 0), VD-2);
    const int loy = min(max(Mny, 0), VD-2);
    const int loz = min(max(Mnz, 0), VD-2);
    const int XL = min(max(Mxx, 0), VD-2) - lox + 2;
    const int YL = min(max(Mxy, 0), VD-2) - loy + 2;
    const int ZL = min(max(Mxz, 0), VD-2) - loz + 2;
    const bool fits = (Mnx <= Mxx) && (XL <= XSTR) && (YL <= 17) && (ZL <= ZMAX);

    // ---- stage slab: async global->LDS, all issues before one drain ----
    // chunk c (64 floats) = plane c/9, in-plane base (c%9)*64; lane adds +lane.
    if (fits) {
        const int NCH = ZL * 9;                        // <= 198 chunks
        for (int c = wv; c < NCH; c += 8) {
            const int zc = c / 9;                      // compile-time divisor
            const int r  = ((c - zc*9) << 6) + lane;   // 0..575
            const int yy = r / XSTR;                   // compile-time divisor
            const int xx = r - yy*XSTR;
            int g = ((loz + zc)*VD + (loy + yy))*VD + (lox + xx);
            g = min(g, VD*VD*VD - 1);                  // pad lanes clamp in-vol
            __builtin_amdgcn_global_load_lds(
                (const __attribute__((address_space(1))) void*)(v + g),
                (__attribute__((address_space(3))) void*)(slab + (c << 6) + lane),
                4, 0, 0);
        }
    }
    __syncthreads();                                   // B3: slab ready (vmcnt drained)

    if (fits && __all(inb)) {
        // ---- interior: all taps from LDS (compile-time strides) ----
        #pragma unroll
        for (int k = 0; k < ODQ; ++k) {
            const float* sb = &slab[(iz[k]-loz)*PLS + (iy[k]-loy)*XSTR + (ix[k]-lox)];
            const float a0 = sb[0],        a1 = sb[1];
            const float a2 = sb[XSTR],     a3 = sb[XSTR+1];
            const float b0 = sb[PLS],      b1 = sb[PLS+1];
            const float b2 = sb[PLS+XSTR], b3 = sb[PLS+XSTR+1];
            const float r00 = fmaf(fx[k], a1 - a0, a0);
            const float r01 = fmaf(fx[k], a3 - a2, a2);
            const float r10 = fmaf(fx[k], b1 - b0, b0);
            const float r11 = fmaf(fx[k], b3 - b2, b2);
            const float r0 = fmaf(fy[k], r01 - r00, r00);
            const float r1 = fmaf(fy[k], r11 - r10, r10);
            op[(size_t)k*OD*OD] = fmaf(fz[k], r1 - r0, r0);
        }
    } else {
        // ---- border / no-fit: predicated-weight global path (proven) ----
        #pragma unroll
        for (int k = 0; k < ODQ; ++k) {
            const int ix1 = ix[k] + 1, iy1 = iy[k] + 1, iz1 = iz[k] + 1;

            const float WX0 = ((unsigned)ix[k] < (unsigned)VD) ? (1.0f - fx[k]) : 0.0f;
            const float WX1 = ((unsigned)ix1   < (unsigned)VD) ? fx[k]          : 0.0f;
            const float WY0 = ((unsigned)iy[k] < (unsigned)VD) ? (1.0f - fy[k]) : 0.0f;
            const float WY1 = ((unsigned)iy1   < (unsigned)VD) ? fy[k]          : 0.0f;
            const float WZ0 = ((unsigned)iz[k] < (unsigned)VD) ? (1.0f - fz[k]) : 0.0f;
            const float WZ1 = ((unsigned)iz1   < (unsigned)VD) ? fz[k]          : 0.0f;

            const int xc0 = min(max(ix[k], 0), VD-1), xc1 = min(max(ix1, 0), VD-1);
            const int yc0 = min(max(iy[k], 0), VD-1), yc1 = min(max(iy1, 0), VD-1);
            const int zc0 = min(max(iz[k], 0), VD-1), zc1 = min(max(iz1, 0), VD-1);

            const int base = min(xc0, VD-2);
            const bool hi0 = (xc0 != base);
            const bool hi1 = (xc1 != base);
            const float wA = (hi0 ? 0.0f : WX0) + (hi1 ? 0.0f : WX1);
            const float wB = (hi0 ? WX0 : 0.0f) + (hi1 ? WX1 : 0.0f);

            const int sA = zc0*(VD*VD), sB = zc1*(VD*VD);
            const int tA = yc0*VD + base, tB = yc1*VD + base;

            float2 p00, p01, p10, p11;
            __builtin_memcpy(&p00, v + sA + tA, sizeof(float2));
            __builtin_memcpy(&p01, v + sA + tB, sizeof(float2));
            __builtin_memcpy(&p10, v + sB + tA, sizeof(float2));
            __builtin_memcpy(&p11, v + sB + tB, sizeof(float2));

            const float r00 = p00.x*wA + p00.y*wB;
            const float r01 = p01.x*wA + p01.y*wB;
            const float r10 = p10.x*wA + p10.y*wB;
            const float r11 = p11.x*wA + p11.y*wB;
            op[(size_t)k*OD*OD] = (r00*WY0 + r01*WY1)*WZ0 + (r10*WY0 + r11*WY1)*WZ1;
        }
    }
}

// ---------------------------------------------------------------------------
extern "C" void kernel_launch(void* const* d_in, const int* in_sizes, int n_in,
                              void* d_out, int out_size, void* d_ws, size_t ws_size,
                              hipStream_t stream) {
    const float* vol   = (const float*)d_in[0];
    const float* rot   = (const float*)d_in[1];
    const float* scale = (const float*)d_in[2];
    const float* shift = (const float*)d_in[3];
    const float* dz    = (const float*)d_in[4];
    const float* dy    = (const float*)d_in[5];
    const float* dx    = (const float*)d_in[6];
    float* out = (float*)d_out;

    float* ws     = (float*)d_ws;
    float* theta  = ws;          // 48 floats
    float* fields = ws + 48;     // 3*1331 = 3993 floats

    prep_kernel<<<4, 1024, 0, stream>>>(rot, scale, shift, dz, dy, dx,
                                        theta, fields);
    dim3 grid(OD/16, OD/8, (OD/8)*NBATCH);
    sample_kernel<<<grid, 512, 0, stream>>>(vol, theta, fields, out);
}

// Round 9
// 138.828 us; speedup vs baseline: 1.3891x; 1.3891x over previous
//
#include <hip/hip_runtime.h>

// Problem constants
#define VD 160           // vol D=H=W
#define OD 128           // output crop size
#define CROP0 16         // (160-128)/2
#define FSZ 11           // cropped field size
#define RAWSZ 15         // raw field size
#define NBATCH 4
#define ODQ 4            // outputs per thread along od

// e-table (LDS): rows [c(3)][oh_l(4)][od_l(8)], row stride ESTR floats.
#define ESTR 17
#define E_CST (32*ESTR)    // channel stride = 544 floats

// ---------------------------------------------------------------------------
// Compile-time (box-5 edge-clamp)^4 as a 15x15 matrix: 4 smoothing iterations
// per axis collapse into one 15-tap linear pass (operators on distinct axes
// commute; per-axis operator is B^4).
// ---------------------------------------------------------------------------
struct M15 { float v[15][15]; };
constexpr M15 mkB() {
    M15 b{};
    for (int i = 0; i < 15; ++i)
        for (int j = 0; j < 15; ++j) b.v[i][j] = 0.0f;
    for (int i = 0; i < 15; ++i)
        for (int t = -2; t <= 2; ++t) {
            int j = i + t; j = j < 0 ? 0 : (j > 14 ? 14 : j);
            b.v[i][j] += 0.2f;
        }
    return b;
}
constexpr M15 mmul(const M15& a, const M15& b) {
    M15 c{};
    for (int i = 0; i < 15; ++i)
        for (int j = 0; j < 15; ++j) {
            float s = 0.0f;
            for (int k = 0; k < 15; ++k) s += a.v[i][k] * b.v[k][j];
            c.v[i][j] = s;
        }
    return c;
}
constexpr M15 B2 = mmul(mkB(), mkB());
constexpr M15 B4 = mmul(B2, B2);

// ---------------------------------------------------------------------------
// Kernel 1: field prep (blocks 0..2) + Rodrigues/theta (block 3).
// 3 matrix passes (x,y,z) + crop folded in.
// ---------------------------------------------------------------------------
__global__ __launch_bounds__(1024) void prep_kernel(
        const float* __restrict__ rot, const float* __restrict__ scale,
        const float* __restrict__ shift,
        const float* __restrict__ dz, const float* __restrict__ dy,
        const float* __restrict__ dx,
        float* __restrict__ theta, float* __restrict__ fields) {
    const int tid = threadIdx.x;
    const int chan = blockIdx.x;

    if (chan == 3) {
        int n = tid;
        if (n >= NBATCH) return;
        float rx = rot[n*3+0], ry = rot[n*3+1], rz = rot[n*3+2];
        float t2 = rx*rx + ry*ry + rz*rz;
        const float eps = 1e-6f;
        float th = sqrtf(fmaxf(t2, eps));
        float inv = 1.0f / (th + eps);
        float wx = rx*inv, wy = ry*inv, wz = rz*inv;
        float c = cosf(th), s = sinf(th), k = 1.0f - c;
        float R[9];
        if (t2 > eps) {
            R[0] = c + wx*wx*k;      R[1] = wx*wy*k - wz*s;  R[2] = wy*s + wx*wz*k;
            R[3] = wz*s + wx*wy*k;   R[4] = c + wy*wy*k;     R[5] = -wx*s + wy*wz*k;
            R[6] = -wy*s + wx*wz*k;  R[7] = wx*s + wy*wz*k;  R[8] = c + wz*wz*k;
        } else {
            R[0] = 1.0f; R[1] = -rz;  R[2] = ry;
            R[3] = rz;   R[4] = 1.0f; R[5] = -rx;
            R[6] = -ry;  R[7] = rx;   R[8] = 1.0f;
        }
        for (int i = 0; i < 3; ++i) {
            for (int j = 0; j < 3; ++j)
                theta[n*12 + i*4 + j] = R[i*3 + j] * scale[n*3 + j];
            theta[n*12 + i*4 + 3] = shift[n*3 + i];
        }
        return;
    }

    __shared__ float bufA[RAWSZ*RAWSZ*RAWSZ];   // raw scaled  [z][y][x]
    __shared__ float bufB[RAWSZ*RAWSZ*FSZ];     // x-pass out  [z][y][xo]
    __shared__ float bufC[RAWSZ*FSZ*FSZ];       // y-pass out  [z][yo][xo]
    const float* raw = (chan == 0) ? dz : (chan == 1) ? dy : dx;
    const int NTOT = RAWSZ*RAWSZ*RAWSZ;   // 3375

    for (int i = tid; i < NTOT; i += 1024)
        bufA[i] = (raw[i] - 0.5f) * 4.0f;
    __syncthreads();

    // x pass: 15*15*11 = 2475 outputs; out xo = crop row xo+2 of B4
    for (int i = tid; i < RAWSZ*RAWSZ*FSZ; i += 1024) {
        const int zy = i / FSZ;
        const int xo = i % FSZ;
        const float* row = &bufA[zy * RAWSZ];
        const float* w = B4.v[xo + 2];
        float s = 0.0f;
        #pragma unroll
        for (int j = 0; j < RAWSZ; ++j) s += row[j] * w[j];
        bufB[i] = s;
    }
    __syncthreads();

    // y pass: 15*11*11 = 1815 outputs
    for (int i = tid; i < RAWSZ*FSZ*FSZ; i += 1024) {
        const int z  = i / (FSZ*FSZ);
        const int r  = i % (FSZ*FSZ);
        const int yo = r / FSZ;
        const int xo = r % FSZ;
        const float* base = &bufB[z * (RAWSZ*FSZ) + xo];
        const float* w = B4.v[yo + 2];
        float s = 0.0f;
        #pragma unroll
        for (int j = 0; j < RAWSZ; ++j) s += base[j * FSZ] * w[j];
        bufC[i] = s;
    }
    __syncthreads();

    // z pass: 11*11*11 = 1331 outputs -> fields
    for (int i = tid; i < FSZ*FSZ*FSZ; i += 1024) {
        const int zo = i / (FSZ*FSZ);
        const int r  = i % (FSZ*FSZ);
        const float* base = &bufC[r];
        const float* w = B4.v[zo + 2];
        float s = 0.0f;
        #pragma unroll
        for (int j = 0; j < RAWSZ; ++j) s += base[j * (FSZ*FSZ)] * w[j];
        fields[chan*FSZ*FSZ*FSZ + i] = s;
    }
}

// ---------------------------------------------------------------------------
// resize helper: src = (m+0.5)*(11/160) - 0.5, clipped to [0,10]
// ---------------------------------------------------------------------------
__device__ __forceinline__ void resize_coord(int m, int& i0, int& i1, float& w) {
    float s = fmaf((float)m + 0.5f, (float)FSZ / (float)VD, -0.5f);
    s = fminf(fmaxf(s, 0.0f), (float)(FSZ - 1));
    float f = floorf(s);
    i0 = (int)f;
    i1 = min(i0 + 1, FSZ - 1);
    w = s - f;
}

// ---------------------------------------------------------------------------
// Kernel 2: main sampler — SESSION-BEST STRUCTURE (verified 139.59 us total).
// Wave = 64 consecutive ow; block = 512 thr = 8 waves = 4(oh) x 2(wd);
// block tile = 64w x 4h x 8d; each thread does ODQ=4 od's.
//
// Sample sits at the TA/L1 scattered-service wall: 2048 gather wave-instrs/CU
// x ~49cy each (64 divergent addr @ ~4/cy + ~12-17 L1 line transactions under
// rotation) = ~100K cy = ~42us. Proven invariant to: VALU work (R1), MLP depth
// (R5 asm, 16 in flight), lane map (R0 vs R4), e-table location (R3 global:
// +23MB = 8 XCD refetch), LDS restaging (R8 slab: 2.4x worse — overfetch +
// bank conflicts + occupancy loss). This revision = R4 verified artifact.
// grid = (OD/64, OD/4, (OD/8)*NBATCH).
// ---------------------------------------------------------------------------
__global__ __launch_bounds__(512, 4) void sample_kernel(
        const float* __restrict__ vol, const float* __restrict__ theta,
        const float* __restrict__ fields, float* __restrict__ out) {
    __shared__ float e[3*E_CST];   // 96 rows x 17 floats = 6528 B

    const int tid  = threadIdx.x;
    const int lane = tid & 63;
    const int wv   = tid >> 6;         // wave id 0..7
    const int oh_l = wv & 3;
    const int wd   = wv >> 2;          // 0..1

    const int ow   = (blockIdx.x << 6) | lane;      // 0..127
    const int oh   = (blockIdx.y << 2) | oh_l;      // 0..127
    const int odb  = (blockIdx.z & 15) << 3;        // od block base
    const int n    = blockIdx.z >> 4;
    const int od0  = odb + (wd << 2);

    // ---- e fill: 32 rows (oh_l*8+od_l) x 16 xi slots = 512 threads exactly;
    //      3 channels per thread; resize_coord hoisted (2 calls) ----
    {
        const int xi = tid & 15;
        const int rb = tid >> 4;        // 0..31 = oh_l*8 + od_l
        if (xi < FSZ) {
            const int od_l  = rb & 7;
            const int oh_l2 = rb >> 3;
            int zi0, zi1, yi0, yi1; float zw, yw;
            resize_coord(odb + od_l + CROP0, zi0, zi1, zw);
            resize_coord((blockIdx.y << 2) + oh_l2 + CROP0, yi0, yi1, yw);
            const float w00 = (1.0f-zw)*(1.0f-yw), w01 = (1.0f-zw)*yw;
            const float w10 = zw*(1.0f-yw),        w11 = zw*yw;
            const int o00 = zi0*121 + yi0*11 + xi, o01 = zi0*121 + yi1*11 + xi;
            const int o10 = zi1*121 + yi0*11 + xi, o11 = zi1*121 + yi1*11 + xi;
            #pragma unroll
            for (int c = 0; c < 3; ++c) {
                const float* f = fields + c * (FSZ*FSZ*FSZ);
                e[(c*32 + rb)*ESTR + xi] =
                    80.0f * (f[o00]*w00 + f[o01]*w01 + f[o10]*w10 + f[o11]*w11);
            }
        }
    }

    // ---- per-thread setup (before barrier: overlaps e-fill latency) ----
    const int w_ = ow + CROP0;

    const float x = fmaf(2.0f * (float)w_ + 1.0f, 1.0f / (float)VD, -1.0f);
    const float y = fmaf(2.0f * (float)(oh + CROP0) + 1.0f, 1.0f / (float)VD, -1.0f);

    // x-knot: s in [0.63, 9.38] for valid w_ -> xi0<=9, xi1=xi0+1 always
    float s = fmaf((float)w_ + 0.5f, (float)FSZ / (float)VD, -0.5f);
    s = fminf(fmaxf(s, 0.0f), (float)(FSZ - 1));
    const float sf = floorf(s);
    const int   xi0 = (int)sf;
    const float xw  = s - sf;

    const float* th = theta + n*12;
    const float cx = fmaf(th[0]*x + th[1]*y + th[3], 80.0f, 79.5f);
    const float cy = fmaf(th[4]*x + th[5]*y + th[7], 80.0f, 79.5f);
    const float cz = fmaf(th[8]*x + th[9]*y + th[11], 80.0f, 79.5f);
    const float tz0 = th[2] * 80.0f, tz1 = th[6] * 80.0f, tz2 = th[10] * 80.0f;

    const float* v = vol + (size_t)n * (VD*VD*VD);

    // row = oh_l*8 + wd*4 (+k); channel stride E_CST
    const float* ebase = &e[(oh_l*8 + (wd << 2))*ESTR + xi0];

    const float zb = fmaf(2.0f * (float)(od0 + CROP0) + 1.0f,
                          1.0f / (float)VD, -1.0f);
    float* op = out + ((((size_t)n*OD + od0)*OD + oh)*OD + ow);

    __syncthreads();

    // ---- batched e reads: 12 pairs, all independent ----
    float e0[3][ODQ], e1[3][ODQ];
    #pragma unroll
    for (int c = 0; c < 3; ++c)
        #pragma unroll
        for (int k = 0; k < ODQ; ++k) {
            e0[c][k] = ebase[c*E_CST + k*ESTR    ];
            e1[c][k] = ebase[c*E_CST + k*ESTR + 1];
        }

    // ---- batched coords ----
    float fx[ODQ], fy[ODQ], fz[ODQ];
    int ix[ODQ], iy[ODQ], iz[ODQ];
    int inb = 1;
    #pragma unroll
    for (int k = 0; k < ODQ; ++k) {
        const float z = zb + (float)k * (2.0f / (float)VD);
        const float d80x = fmaf(e1[0][k] - e0[0][k], xw, e0[0][k]);
        const float d80y = fmaf(e1[1][k] - e0[1][k], xw, e0[1][k]);
        const float d80z = fmaf(e1[2][k] - e0[2][k], xw, e0[2][k]);
        const float xs = fmaf(tz0, z, cx) + d80x;
        const float ys = fmaf(tz1, z, cy) + d80y;
        const float zs = fmaf(tz2, z, cz) + d80z;
        const float x0f = floorf(xs), y0f = floorf(ys), z0f = floorf(zs);
        fx[k] = xs - x0f; fy[k] = ys - y0f; fz[k] = zs - z0f;
        ix[k] = (int)x0f; iy[k] = (int)y0f; iz[k] = (int)z0f;
        inb &= ((unsigned)ix[k] < (unsigned)(VD-1)) &
               ((unsigned)iy[k] < (unsigned)(VD-1)) &
               ((unsigned)iz[k] < (unsigned)(VD-1));
    }

    if (__all(inb)) {
        // ---- interior fast path: all 16 gathers batched before consumption ----
        float2 p00[ODQ], p01[ODQ], p10[ODQ], p11[ODQ];
        #pragma unroll
        for (int k = 0; k < ODQ; ++k) {
            const int b00 = (iz[k]*VD + iy[k])*VD + ix[k];
            __builtin_memcpy(&p00[k], v + b00,            sizeof(float2));
            __builtin_memcpy(&p01[k], v + b00 + VD,       sizeof(float2));
            __builtin_memcpy(&p10[k], v + b00 + VD*VD,    sizeof(float2));
            __builtin_memcpy(&p11[k], v + b00 + VD*VD+VD, sizeof(float2));
        }
        __builtin_amdgcn_sched_barrier(0);
        #pragma unroll
        for (int k = 0; k < ODQ; ++k)
            asm volatile("" :: "v"(p00[k].x), "v"(p00[k].y),
                               "v"(p01[k].x), "v"(p01[k].y),
                               "v"(p10[k].x), "v"(p10[k].y),
                               "v"(p11[k].x), "v"(p11[k].y));
        #pragma unroll
        for (int k = 0; k < ODQ; ++k) {
            const float r00 = fmaf(fx[k], p00[k].y - p00[k].x, p00[k].x);
            const float r01 = fmaf(fx[k], p01[k].y - p01[k].x, p01[k].x);
            const float r10 = fmaf(fx[k], p10[k].y - p10[k].x, p10[k].x);
            const float r11 = fmaf(fx[k], p11[k].y - p11[k].x, p11[k].x);
            const float r0 = fmaf(fy[k], r01 - r00, r00);
            const float r1 = fmaf(fy[k], r11 - r10, r10);
            op[(size_t)k*OD*OD] = fmaf(fz[k], r1 - r0, r0);
        }
    } else {
        // ---- border path: full predicated weights + clamps (rare) ----
        #pragma unroll
        for (int k = 0; k < ODQ; ++k) {
            const int ix1 = ix[k] + 1, iy1 = iy[k] + 1, iz1 = iz[k] + 1;

            const float WX0 = ((unsigned)ix[k] < (unsigned)VD) ? (1.0f - fx[k]) : 0.0f;
            const float WX1 = ((unsigned)ix1   < (unsigned)VD) ? fx[k]          : 0.0f;
            const float WY0 = ((unsigned)iy[k] < (unsigned)VD) ? (1.0f - fy[k]) : 0.0f;
            const float WY1 = ((unsigned)iy1   < (unsigned)VD) ? fy[k]          : 0.0f;
            const float WZ0 = ((unsigned)iz[k] < (unsigned)VD) ? (1.0f - fz[k]) : 0.0f;
            const float WZ1 = ((unsigned)iz1   < (unsigned)VD) ? fz[k]          : 0.0f;

            const int xc0 = min(max(ix[k], 0), VD-1), xc1 = min(max(ix1, 0), VD-1);
            const int yc0 = min(max(iy[k], 0), VD-1), yc1 = min(max(iy1, 0), VD-1);
            const int zc0 = min(max(iz[k], 0), VD-1), zc1 = min(max(iz1, 0), VD-1);

            // one dwordx2 covers both x-taps; fold x-selection into wA/wB
            const int base = min(xc0, VD-2);
            const bool hi0 = (xc0 != base);
            const bool hi1 = (xc1 != base);
            const float wA = (hi0 ? 0.0f : WX0) + (hi1 ? 0.0f : WX1);
            const float wB = (hi0 ? WX0 : 0.0f) + (hi1 ? WX1 : 0.0f);

            const int sA = zc0*(VD*VD), sB = zc1*(VD*VD);
            const int tA = yc0*VD + base, tB = yc1*VD + base;

            float2 p00, p01, p10, p11;
            __builtin_memcpy(&p00, v + sA + tA, sizeof(float2));
            __builtin_memcpy(&p01, v + sA + tB, sizeof(float2));
            __builtin_memcpy(&p10, v + sB + tA, sizeof(float2));
            __builtin_memcpy(&p11, v + sB + tB, sizeof(float2));

            const float r00 = p00.x*wA + p00.y*wB;
            const float r01 = p01.x*wA + p01.y*wB;
            const float r10 = p10.x*wA + p10.y*wB;
            const float r11 = p11.x*wA + p11.y*wB;
            op[(size_t)k*OD*OD] = (r00*WY0 + r01*WY1)*WZ0 + (r10*WY0 + r11*WY1)*WZ1;
        }
    }
}

// ---------------------------------------------------------------------------
extern "C" void kernel_launch(void* const* d_in, const int* in_sizes, int n_in,
                              void* d_out, int out_size, void* d_ws, size_t ws_size,
                              hipStream_t stream) {
    const float* vol   = (const float*)d_in[0];
    const float* rot   = (const float*)d_in[1];
    const float* scale = (const float*)d_in[2];
    const float* shift = (const float*)d_in[3];
    const float* dz    = (const float*)d_in[4];
    const float* dy    = (const float*)d_in[5];
    const float* dx    = (const float*)d_in[6];
    float* out = (float*)d_out;

    float* ws     = (float*)d_ws;
    float* theta  = ws;          // 48 floats
    float* fields = ws + 48;     // 3*1331 = 3993 floats

    prep_kernel<<<4, 1024, 0, stream>>>(rot, scale, shift, dz, dy, dx,
                                        theta, fields);
    dim3 grid(OD/64, OD/4, (OD/8)*NBATCH);
    sample_kernel<<<grid, 512, 0, stream>>>(vol, theta, fields, out);
}